// Round 1
// 11117.824 us; speedup vs baseline: 1.8730x; 1.8730x over previous
//
#include <hip/hip_runtime.h>

// 2-layer LSTM, B=64, T=1024, D_IN=256, H=512, fp32 in/out.
// R4 (this round), on top of R3's MFMA split-bf16 + relaxed-agent write-through scheme:
//  - h buffers TRANSPOSED to [k][b] (hidden-major, batch contiguous):
//      * cell h-store: 16 full 64B lines/block (was 256 scattered 4B partials)
//      * h fragment loads: each 64-lane dword load reads 4 fully-used lines
//  - FULL-STEP PREFETCH: all 128 raw dwords issued into registers before any
//    unpack/MFMA (one exposed L3 round-trip instead of ~16); launch_bounds(512,2)
//    raises the VGPR cap to 256 (1 block/CU unchanged).
//  - FLAT FLAG BARRIER: per-block monotonic epoch flags, store-only (no RMW);
//    threads 0..255 poll one flag each (1 wave instr covers 64 flags).
// Memory model identical to R3 (verified): write-through relaxed AGENT atomic
// stores, vmcnt drained by __syncthreads before flag store; sc1 atomic loads
// bypass stale L1/L2 on the consumer side. Monotonic counters, no resets.

#define BB   64
#define TT   1024
#define DIN  256
#define HH   512
#define K0   768     // [h0_prev(512) | x_t(256)]
#define K1   1024    // [h1_prev(512) | h0_t(512)]
#define NTHR 512

typedef float f32x4 __attribute__((ext_vector_type(4)));
typedef short short8 __attribute__((ext_vector_type(8)));

union S8U4 { short8 s; unsigned u[4]; };
union RawU { unsigned u[8]; f32x4 v[2]; };   // 8 packed h-words OR 8 x-floats

__device__ __forceinline__ void splitf(float f, short& h, short& l) {
    const unsigned u = __float_as_uint(f);
    const float fh = __uint_as_float(u & 0xffff0000u);
    h = (short)(u >> 16);
    l = (short)(__float_as_uint(f - fh) >> 16);
}

__device__ __forceinline__ void split8(f32x4 a, f32x4 b, short8& hi, short8& lo) {
#pragma unroll
    for (int j = 0; j < 4; ++j) {
        short h0, l0, h1, l1;
        splitf(a[j], h0, l0);
        splitf(b[j], h1, l1);
        hi[j] = h0; lo[j] = l0;
        hi[j + 4] = h1; lo[j + 4] = l1;
    }
}

__device__ __forceinline__ unsigned packhl(float f) {
    const unsigned u = __float_as_uint(f);
    const float fh = __uint_as_float(u & 0xffff0000u);
    const unsigned l = __float_as_uint(f - fh) >> 16;
    return (u >> 16) | (l << 16);     // bytes 0-1: hi bf16, bytes 2-3: lo bf16
}

__global__ __launch_bounds__(NTHR, 2) void lstm_fused(
    const float* __restrict__ x,
    const float* __restrict__ W0, const float* __restrict__ b0v,
    const float* __restrict__ W1, const float* __restrict__ b1v,
    float* __restrict__ out, unsigned* __restrict__ hws, unsigned* __restrict__ bar)
{
    __shared__ float Red[8][16][68];    // per-wave K-partials, padded (34.8 KB)
    __shared__ float Gb[BB][17];        // gates regroup (4.4 KB)
    __shared__ float biasl[16];

    const int tid   = threadIdx.x;
    const int bid   = blockIdx.x;
    const int layer = bid >> 7;
    const int hbase = (bid & 127) << 2;

    const float* Wm = layer ? W1 : W0;
    const float* bv = layer ? b1v : b0v;
    const int K     = layer ? K1 : K0;

    // packed (hi|lo) h buffers, TRANSPOSED: [2 parities][512 k][64 b] u32
    unsigned* HP0 = hws;
    unsigned* HP1 = hws + 2 * BB * HH;

    if (tid < 16)
        biasl[tid] = bv[(tid >> 2) * HH + hbase + (tid & 3)];

    const int w     = tid >> 6;        // wave 0..7 (K-slice owner)
    const int lane  = tid & 63;
    const int quad  = lane >> 4;       // 0..3
    const int lm    = lane & 15;       // fragment row (m or n)
    const int kbase = w << 7;          // wave's K offset (128 each)
    const int grow  = (lm >> 2) * HH + hbase + (lm & 3);

    // ---- persistent W fragments: hi/lo bf16, 4 k-steps of 32 ----
    short8 whi[4], wlo[4];
#pragma unroll
    for (int ks = 0; ks < 4; ++ks) {
        short8 hi = {0, 0, 0, 0, 0, 0, 0, 0};
        short8 lo = {0, 0, 0, 0, 0, 0, 0, 0};
        const int kb = kbase + ks * 32;
        if (kb < K) {
            const int k0 = kb + quad * 8;
            const float* p = Wm + (size_t)grow * K + k0;
            split8(*(const f32x4*)p, *(const f32x4*)(p + 4), hi, lo);
        }
        whi[ks] = hi; wlo[ks] = lo;
    }
    __syncthreads();

    float creg = 0.0f;                 // persistent cell state (tid<256)
    unsigned epoch = 0;
    const size_t YOFF = (size_t)BB * TT * HH;

    for (int s = 0; s <= TT; ++s) {
        const bool active = layer ? (s >= 1) : (s < TT);
        if (active) {
            const int t   = layer ? (s - 1) : s;
            const int par = (s & 1) * BB * HH;
            const unsigned* hp = (layer ? HP1 : HP0) + par;
            const unsigned* hc = HP0 + par;   // layer1: h0 of current t

            // ---- PHASE 1: issue ALL fragment loads (deep vmcnt pipeline) ----
            RawU raw[4][4];   // [ks][nt], 8 dwords each: 128 VGPRs in flight
#pragma unroll
            for (int ks = 0; ks < 4; ++ks) {
                const int kb = kbase + ks * 32;
                if (kb < K) {
                    const int k0 = kb + quad * 8;
                    if (kb < HH) {
#pragma unroll
                        for (int nt = 0; nt < 4; ++nt) {
                            const int n = (nt << 4) + lm;
                            const unsigned* p = hp + (size_t)k0 * BB + n;
#pragma unroll
                            for (int j = 0; j < 8; ++j)
                                raw[ks][nt].u[j] = __hip_atomic_load(
                                    p + (size_t)j * BB,
                                    __ATOMIC_RELAXED, __HIP_MEMORY_SCOPE_AGENT);
                        }
                    } else if (layer) {
#pragma unroll
                        for (int nt = 0; nt < 4; ++nt) {
                            const int n = (nt << 4) + lm;
                            const unsigned* p = hc + (size_t)(k0 - HH) * BB + n;
#pragma unroll
                            for (int j = 0; j < 8; ++j)
                                raw[ks][nt].u[j] = __hip_atomic_load(
                                    p + (size_t)j * BB,
                                    __ATOMIC_RELAXED, __HIP_MEMORY_SCOPE_AGENT);
                        }
                    } else {
#pragma unroll
                        for (int nt = 0; nt < 4; ++nt) {
                            const int n = (nt << 4) + lm;
                            const float* p = x + ((size_t)n * TT + t) * DIN + (k0 - HH);
                            raw[ks][nt].v[0] = *(const f32x4*)p;
                            raw[ks][nt].v[1] = *(const f32x4*)(p + 4);
                        }
                    }
                }
            }

            // ---- PHASE 2: unpack + MFMA (consumes loads in issue order) ----
            f32x4 acc[4];
#pragma unroll
            for (int nt = 0; nt < 4; ++nt) acc[nt] = (f32x4){0.f, 0.f, 0.f, 0.f};

#pragma unroll
            for (int ks = 0; ks < 4; ++ks) {
                const int kb = kbase + ks * 32;
                if (kb < K) {
#pragma unroll
                    for (int nt = 0; nt < 4; ++nt) {
                        short8 chi, clo;
                        if (!layer && kb >= HH) {
                            split8(raw[ks][nt].v[0], raw[ks][nt].v[1], chi, clo);
                        } else {
                            S8U4 hi, lo;
#pragma unroll
                            for (int j2 = 0; j2 < 4; ++j2) {
                                const unsigned u0 = raw[ks][nt].u[2 * j2];
                                const unsigned u1 = raw[ks][nt].u[2 * j2 + 1];
                                hi.u[j2] = __builtin_amdgcn_perm(u1, u0, 0x05040100u);
                                lo.u[j2] = __builtin_amdgcn_perm(u1, u0, 0x07060302u);
                            }
                            chi = hi.s; clo = lo.s;
                        }
                        acc[nt] = __builtin_amdgcn_mfma_f32_16x16x32_bf16(whi[ks], chi, acc[nt], 0, 0, 0);
                        acc[nt] = __builtin_amdgcn_mfma_f32_16x16x32_bf16(whi[ks], clo, acc[nt], 0, 0, 0);
                        acc[nt] = __builtin_amdgcn_mfma_f32_16x16x32_bf16(wlo[ks], chi, acc[nt], 0, 0, 0);
                    }
                }
            }

            // ---- dump K-partials: D[m=quad*4+r][n=nt*16+lm] ----
#pragma unroll
            for (int nt = 0; nt < 4; ++nt)
#pragma unroll
                for (int r = 0; r < 4; ++r)
                    Red[w][quad * 4 + r][(nt << 4) + lm] = acc[nt][r];
            __syncthreads();
            // ---- 8-way reduce + bias ----
            {
                const int row = tid & 15, b0 = tid >> 4;
                float s0 = biasl[row], s1 = biasl[row];
#pragma unroll
                for (int ww = 0; ww < 8; ++ww) {
                    s0 += Red[ww][row][b0];
                    s1 += Red[ww][row][b0 + 32];
                }
                Gb[b0][row] = s0;
                Gb[b0 + 32][row] = s1;
            }
            __syncthreads();
            // ---- cell: 256 threads, one (b, hh) each; c stays in creg ----
            if (tid < 256) {
                const int b   = tid & 63;
                const int hh2 = tid >> 6;
                const float ig = Gb[b][hh2];
                const float fg = Gb[b][4 + hh2];
                const float gg = Gb[b][8 + hh2];
                const float og = Gb[b][12 + hh2];
                const float si = 1.0f / (1.0f + __expf(-ig));
                const float sf = 1.0f / (1.0f + __expf(-fg));
                const float so = 1.0f / (1.0f + __expf(-og));
                const float c  = sf * creg + si * tanhf(gg);
                creg = c;
                const float h  = so * tanhf(c);
                const int hidx = hbase + hh2;
                const int wpar = ((s + 1) & 1) * BB * HH;
                const unsigned packed = packhl(h);
                // transposed store: consecutive tids (b) -> consecutive addrs
                if (layer == 0) {
                    __hip_atomic_store(&HP0[wpar + hidx * BB + b], packed,
                                       __ATOMIC_RELAXED, __HIP_MEMORY_SCOPE_AGENT);
                    if (t == TT - 1) {
                        out[YOFF + (size_t)b * HH + hidx] = h;                 // h_n[0]
                        out[YOFF + 2 * BB * HH + (size_t)b * HH + hidx] = c;   // c_n[0]
                    }
                } else {
                    out[((size_t)b * TT + t) * HH + hidx] = h;                 // y[b,t,:]
                    __hip_atomic_store(&HP1[wpar + hidx * BB + b], packed,
                                       __ATOMIC_RELAXED, __HIP_MEMORY_SCOPE_AGENT);
                    if (t == TT - 1) {
                        out[YOFF + BB * HH + (size_t)b * HH + hidx] = h;       // h_n[1]
                        out[YOFF + 3 * BB * HH + (size_t)b * HH + hidx] = c;   // c_n[1]
                    }
                }
            }
        }
        // ---- flat flag barrier: store-only, per-block monotonic epochs ----
        if (s < TT) {
            __syncthreads();   // drains each thread's vmcnt -> sc1 stores visible
            ++epoch;
            if (tid == 0) {
                asm volatile("s_waitcnt vmcnt(0)" ::: "memory");
                __hip_atomic_store(&bar[bid], epoch,
                                   __ATOMIC_RELAXED, __HIP_MEMORY_SCOPE_AGENT);
            }
            if (tid < 256) {   // 4 waves, each poll covers 64 consecutive flags
                while (__hip_atomic_load(&bar[tid], __ATOMIC_RELAXED,
                                         __HIP_MEMORY_SCOPE_AGENT) < epoch)
                    __builtin_amdgcn_s_sleep(1);
            }
            __syncthreads();
        }
    }
}

extern "C" void kernel_launch(void* const* d_in, const int* in_sizes, int n_in,
                              void* d_out, int out_size, void* d_ws, size_t ws_size,
                              hipStream_t stream) {
    (void)in_sizes; (void)n_in; (void)out_size; (void)ws_size;
    const float* x  = (const float*)d_in[0];
    const float* W0 = (const float*)d_in[1];
    const float* b0 = (const float*)d_in[2];
    const float* W1 = (const float*)d_in[3];
    const float* b1 = (const float*)d_in[4];
    float* out = (float*)d_out;
    unsigned* hws = (unsigned*)d_ws;  // 2 buffers x [2][512][64] u32 = 512 KB
    unsigned* bar = (unsigned*)((char*)d_ws + 2 * 2 * 64 * 512 * sizeof(unsigned));

    hipMemsetAsync(d_ws, 0, 2 * 2 * 64 * 512 * sizeof(unsigned) + 4096, stream);

    void* args[] = { (void*)&x, (void*)&W0, (void*)&b0, (void*)&W1, (void*)&b1,
                     (void*)&out, (void*)&hws, (void*)&bar };
    hipLaunchCooperativeKernel(reinterpret_cast<const void*>(lstm_fused),
                               dim3(256), dim3(512), args, 0u, stream);
}